// Round 2
// baseline (505.681 us; speedup 1.0000x reference)
//
#include <hip/hip_runtime.h>
#include <math.h>

// Problem constants (from reference): B=32, H=512, N=64, NUM_PROPS=2080
#define PB 32
#define PH 512
#define PN 64
#define PP 2080

// out layout (floats), concatenated in reference return order:
//   [0,        B*P*H)                  props_h  (B, P, H)
//   [OFF_MAP,  OFF_MAP + B*H*64*64)    ori_map_h(B, H, 64, 64)
//   [OFF_MASK, OFF_MASK + B*64*64)     mask     (B, 1, 64, 64)
#define OFF_MAP  ((size_t)PB * PP * PH)
#define OFF_MASK (OFF_MAP + (size_t)PB * PH * PN * PN)

// Valid (s,e) pairs written by the pyramid (traced from _pool_specs):
//   scale0: d=e-s in [0,15], any s
//   scale1: d in {17,19,...,31} (odd), s even
//   scale2: d in {35,39,...,63} (d%4==3), s%4==0
// (e<=63 is implied by the caller's e range)
__device__ __forceinline__ bool pair_valid(int s, int e) {
    int d = e - s;
    if (d < 0) return false;
    if (d <= 15) return true;
    if (d <= 31) return (d & 1) && !(s & 1);
    return d >= 35 && ((d & 3) == 3) && !(s & 3);
}

// One wave per (b,h) row. Lane = e. s descends 63..0; M tracks max x[s..lane]
// (accumulate predicated on s<=lane).
__global__ __launch_bounds__(64) void map_kernel(const float* __restrict__ x,
                                                 float* __restrict__ out) {
    const int bid  = blockIdx.x;          // b*H + h
    const int lane = threadIdx.x;         // e
    __shared__ float sx[PN];

    sx[lane] = x[(size_t)bid * PN + lane];
    __syncthreads();

    const int h = bid & (PH - 1);
    const int b = bid >> 9;               // /512
    float* mrow = out + OFF_MAP + (size_t)bid * (PN * PN);
    float* krow = out + OFF_MASK + (size_t)b * (PN * PN);
    const bool write_mask = (h == 0);

    float M = -INFINITY;
#pragma unroll 1
    for (int s = PN - 1; s >= 0; --s) {
        const float v = sx[s];                       // LDS broadcast read
        if (s <= lane) M = fmaxf(M, v);              // window max x[s..lane]
        const bool good = (lane >= s) && pair_valid(s, lane);
        mrow[s * PN + lane] = good ? M : 0.0f;
        if (write_mask) krow[s * PN + lane] = good ? 1.0f : 0.0f;
    }
}

// props_h: grid (p_chunks, h_tiles=8, b=32), block = 64 threads (lane = local h).
// Stage x[b, h0:h0+64, :] transposed in LDS; all lanes share the (s,e) of a prop
// (uniform control flow), each computes the window max for its h.
#define P_CHUNKS 13
#define PC (PP / P_CHUNKS)   // 160
__global__ __launch_bounds__(64) void props_kernel(const float* __restrict__ x,
                                                   const int* __restrict__ props,
                                                   float* __restrict__ out) {
    const int b    = blockIdx.z;
    const int h0   = blockIdx.y * 64;
    const int p0   = blockIdx.x * PC;
    const int lane = threadIdx.x;

    __shared__ float sx[PN * 65];         // [n][h_local], +1 pad -> 2-way bank alias (free)

    const float* xb = x + ((size_t)b * PH + h0) * PN;
#pragma unroll 4
    for (int i = 0; i < 64; ++i) {
        // i = h_local, lane = n: coalesced 256B row load
        sx[lane * 65 + i] = xb[i * PN + lane];
    }
    __syncthreads();

    float* op = out + (size_t)b * PP * PH + h0;
#pragma unroll 1
    for (int p = p0; p < p0 + PC; ++p) {
        const int s  = props[2 * p];
        const int e1 = props[2 * p + 1] - 1;
        float m = 0.0f;
        if (e1 >= s && pair_valid(s, e1)) {
            m = -INFINITY;
            for (int n = s; n <= e1; ++n)
                m = fmaxf(m, sx[n * 65 + lane]);
        }
        op[(size_t)p * PH + lane] = m;    // coalesced 256B store
    }
}

// Scatter 1.0 into mask at (start, end-1) for every (b,p). Idempotent;
// runs after map_kernel on the same stream.
__global__ void mask_props_kernel(const int* __restrict__ props,
                                  float* __restrict__ out) {
    const int idx = blockIdx.x * blockDim.x + threadIdx.x;
    if (idx >= PB * PP) return;
    const int b = idx / PP;
    const int p = idx - b * PP;
    const int s  = props[2 * p];
    const int e1 = props[2 * p + 1] - 1;
    out[OFF_MASK + (size_t)b * (PN * PN) + s * PN + e1] = 1.0f;
}

extern "C" void kernel_launch(void* const* d_in, const int* in_sizes, int n_in,
                              void* d_out, int out_size, void* d_ws, size_t ws_size,
                              hipStream_t stream) {
    const float* x = (const float*)d_in[0];
    const int* props = (const int*)d_in[1];   // harness passes integer inputs as int32
    float* out = (float*)d_out;

    // K1: ori_map_h + base mask
    map_kernel<<<PB * PH, 64, 0, stream>>>(x, out);
    // K2: props_h
    dim3 g2(P_CHUNKS, PH / 64, PB);
    props_kernel<<<g2, 64, 0, stream>>>(x, props, out);
    // K3: mask scatter at prop pairs
    mask_props_kernel<<<(PB * PP + 255) / 256, 256, 0, stream>>>(props, out);
}

// Round 3
// 485.756 us; speedup vs baseline: 1.0410x; 1.0410x over previous
//
#include <hip/hip_runtime.h>
#include <math.h>

// Problem constants: B=32, H=512, N=64, NUM_PROPS=2080
#define PB 32
#define PH 512
#define PN 64
#define PP 2080

// out layout (floats), reference return order:
//   [0,        OFF_MAP)   props_h  (B, P, H)
//   [OFF_MAP,  OFF_MASK)  ori_map_h(B, H, 64, 64)
//   [OFF_MASK, ...)       mask     (B, 1, 64, 64)
#define OFF_MAP  ((size_t)PB * PP * PH)
#define OFF_MASK (OFF_MAP + (size_t)PB * PH * PN * PN)

// Valid (s,e) pairs written by the pyramid (traced from _pool_specs):
//   scale0: d=e-s in [0,15], any s
//   scale1: d in {17,19,...,31} (odd), s even
//   scale2: d in {35,39,...,63} (d%4==3), s%4==0
__device__ __forceinline__ bool pair_valid(int s, int e) {
    int d = e - s;
    if (d < 0) return false;
    if (d <= 15) return true;
    if (d <= 31) return (d & 1) && !(s & 1);
    return d >= 35 && ((d & 3) == 3) && !(s & 3);
}

// ---------------------------------------------------------------------------
// K1: ori_map_h. One block (256 thr) handles 8 (b,h) rows.
// Sparse max table per row in LDS: level k holds max x[i..i+2^k-1].
// Window max [s,e] = max(L[k][s], L[k][e+1-2^k]), k = min(floor(log2(d+1)),5).
// Invalid pairs resolve to a zero slot -> branch-free emit, float4 stores.
// ---------------------------------------------------------------------------
#define K1_ROWS 8
#define K1_RS 385   // 6 levels * 64 + 1 zero slot (stride breaks bank patterns)

__global__ __launch_bounds__(256) void map_kernel(const float* __restrict__ x,
                                                  float* __restrict__ out) {
    __shared__ float L[K1_ROWS * K1_RS];   // 12.3 KB
    const int tid = threadIdx.x;

    // Per-thread metadata for its 16 (s,e) pairs — identical for all 8 rows.
    int a1[16], a2[16];
#pragma unroll
    for (int j = 0; j < 4; ++j) {
#pragma unroll
        for (int q = 0; q < 4; ++q) {
            const int idx = j * 4 + q;
            const int lin = j * 1024 + tid * 4 + q;   // s*64+e
            const int s = lin >> 6, e = lin & 63;
            const bool good = pair_valid(s, e);
            const int du = (e - s) + 1;
            const int k = good ? min(31 - __clz(du), 5) : 0;
            a1[idx] = good ? k * 64 + s : 384;                 // 384 = zero slot
            a2[idx] = good ? k * 64 + (e + 1 - (1 << k)) : 384;
        }
    }

    // Stage 8 x-rows (level 0) + zero slots.
    const size_t rowBase = (size_t)blockIdx.x * K1_ROWS;
#pragma unroll
    for (int i = tid; i < K1_ROWS * 64; i += 256) {
        const int r = i >> 6, c = i & 63;
        L[r * K1_RS + c] = x[rowBase * 64 + i];       // coalesced
    }
    if (tid < K1_ROWS) L[tid * K1_RS + 384] = 0.0f;
    __syncthreads();

    // Build levels 1..5 (entries past the queried range are garbage-but-unread).
#pragma unroll
    for (int k = 1; k <= 5; ++k) {
        const int off = 1 << (k - 1);
#pragma unroll
        for (int i = tid; i < K1_ROWS * 64; i += 256) {
            const int r = i >> 6, c = i & 63;
            const float* Lp = L + r * K1_RS + (k - 1) * 64;
            L[r * K1_RS + k * 64 + c] = fmaxf(Lp[c], Lp[min(c + off, 63)]);
        }
        __syncthreads();
    }

    // Emit 8 rows, float4 stores (4 KB per wave-instruction across the block).
#pragma unroll 1
    for (int r = 0; r < K1_ROWS; ++r) {
        const float* Lr = L + r * K1_RS;
        float4* orow = (float4*)(out + OFF_MAP + (rowBase + r) * 4096);
#pragma unroll
        for (int j = 0; j < 4; ++j) {
            float4 v;
            v.x = fmaxf(Lr[a1[j * 4 + 0]], Lr[a2[j * 4 + 0]]);
            v.y = fmaxf(Lr[a1[j * 4 + 1]], Lr[a2[j * 4 + 1]]);
            v.z = fmaxf(Lr[a1[j * 4 + 2]], Lr[a2[j * 4 + 2]]);
            v.w = fmaxf(Lr[a1[j * 4 + 3]], Lr[a2[j * 4 + 3]]);
            orow[j * 256 + tid] = v;
        }
    }
}

// ---------------------------------------------------------------------------
// K2: props_h. Block (256 thr) = (prop-chunk of 160, 32-h-tile, b).
// Sparse table over n for 32 h-lanes in LDS (52 KB, 3 blocks/CU).
// Props pre-resolved to (addr1, addr2) LDS pairs (invalid -> zero row);
// main loop: 2 broadcast addr reads + 2 table reads + fmax + store. No branches.
// ---------------------------------------------------------------------------
#define K2_LVL 2112            // 64 * 33 floats per level
#define K2_ZROW (6 * K2_LVL)   // zero row (33 floats)
#define K2_PA (K2_ZROW + 33)   // prop addr pairs (ints)
#define K2_PC 160
#define K2_CHUNKS 13

__global__ __launch_bounds__(256) void props_kernel(const float* __restrict__ x,
                                                    const int* __restrict__ props,
                                                    float* __restrict__ out) {
    __shared__ float Lf[K2_PA + 2 * K2_PC];   // 13025 floats = 52.1 KB
    int* Li = (int*)Lf;

    const int tid = threadIdx.x;
    const int b  = blockIdx.z;
    const int h0 = blockIdx.y * 32;
    const int p0 = blockIdx.x * K2_PC;

    // Stage x[b, h0:h0+32, :] transposed: xT[n][h] at n*33+h (level 0).
    const float* xb = x + ((size_t)b * PH + h0) * PN;
#pragma unroll
    for (int i = tid; i < 32 * 64; i += 256) {
        const int h = i >> 6, n = i & 63;
        Lf[n * 33 + h] = xb[i];               // coalesced read, conflict-free write
    }
    if (tid < 33) Lf[K2_ZROW + tid] = 0.0f;

    // Resolve this chunk's props to LDS address pairs.
    if (tid < K2_PC) {
        const int p  = p0 + tid;
        const int s  = props[2 * p];
        const int e1 = props[2 * p + 1] - 1;
        const bool good = pair_valid(s, e1);  // covers e1 < s
        const int k = good ? min(31 - __clz(e1 - s + 1), 5) : 0;
        Li[K2_PA + 2 * tid]     = good ? k * K2_LVL + s * 33 : K2_ZROW;
        Li[K2_PA + 2 * tid + 1] = good ? k * K2_LVL + (e1 + 1 - (1 << k)) * 33 : K2_ZROW;
    }
    __syncthreads();

    // Build levels 1..5.
#pragma unroll 1
    for (int k = 1; k <= 5; ++k) {
        const int off = 1 << (k - 1);
#pragma unroll
        for (int i = tid; i < 64 * 32; i += 256) {
            const int n = i >> 5, h = i & 31;
            const float* Lp = Lf + (k - 1) * K2_LVL;
            Lf[k * K2_LVL + n * 33 + h] = fmaxf(Lp[n * 33 + h], Lp[min(n + off, 63) * 33 + h]);
        }
        __syncthreads();
    }

    // Each wave: lanes 0..31 = prop A, lanes 32..63 = prop B; 2 props/step.
    const int wave = tid >> 6;
    const int sub  = (tid >> 5) & 1;
    const int h    = tid & 31;
    float* ob = out + (size_t)b * PP * PH + h0 + h;
#pragma unroll 2
    for (int i = 0; i < K2_PC / 8; ++i) {
        const int idx = i * 8 + wave * 2 + sub;
        const int a1 = Li[K2_PA + 2 * idx];
        const int a2 = Li[K2_PA + 2 * idx + 1];
        const float v = fmaxf(Lf[a1 + h], Lf[a2 + h]);
        ob[(size_t)(p0 + idx) * PH] = v;
    }
}

// ---------------------------------------------------------------------------
// K3a: base mask (valid pairs -> 1, else 0), float4 stores.
// ---------------------------------------------------------------------------
__global__ void mask_base_kernel(float* __restrict__ out) {
    const int gid = blockIdx.x * blockDim.x + threadIdx.x;  // over PB*1024
    const int l4 = (gid & 1023) * 4;                        // linear within 64x64
    float4 v;
    float* vv = (float*)&v;
#pragma unroll
    for (int q = 0; q < 4; ++q) {
        const int lin = l4 + q;
        vv[q] = pair_valid(lin >> 6, lin & 63) ? 1.0f : 0.0f;
    }
    ((float4*)(out + OFF_MASK))[gid] = v;
}

// K3b: scatter 1.0 at prop pairs (after K3a on the stream).
__global__ void mask_props_kernel(const int* __restrict__ props,
                                  float* __restrict__ out) {
    const int idx = blockIdx.x * blockDim.x + threadIdx.x;
    if (idx >= PB * PP) return;
    const int b = idx / PP;
    const int p = idx - b * PP;
    const int s  = props[2 * p];
    const int e1 = props[2 * p + 1] - 1;
    out[OFF_MASK + (size_t)b * (PN * PN) + s * PN + e1] = 1.0f;
}

extern "C" void kernel_launch(void* const* d_in, const int* in_sizes, int n_in,
                              void* d_out, int out_size, void* d_ws, size_t ws_size,
                              hipStream_t stream) {
    const float* x = (const float*)d_in[0];
    const int* props = (const int*)d_in[1];   // integer inputs arrive as int32
    float* out = (float*)d_out;

    map_kernel<<<(PB * PH) / K1_ROWS, 256, 0, stream>>>(x, out);

    dim3 g2(K2_CHUNKS, PH / 32, PB);
    props_kernel<<<g2, 256, 0, stream>>>(x, props, out);

    mask_base_kernel<<<(PB * 1024) / 256, 256, 0, stream>>>(out);
    mask_props_kernel<<<(PB * PP + 255) / 256, 256, 0, stream>>>(props, out);
}

// Round 4
// 483.537 us; speedup vs baseline: 1.0458x; 1.0046x over previous
//
#include <hip/hip_runtime.h>
#include <math.h>

// Problem constants: B=32, H=512, N=64, NUM_PROPS=2080
#define PB 32
#define PH 512
#define PN 64
#define PP 2080

// out layout (floats), reference return order:
//   [0,        OFF_MAP)   props_h  (B, P, H)
//   [OFF_MAP,  OFF_MASK)  ori_map_h(B, H, 64, 64)
//   [OFF_MASK, ...)       mask     (B, 1, 64, 64)
#define OFF_MAP  ((size_t)PB * PP * PH)
#define OFF_MASK (OFF_MAP + (size_t)PB * PH * PN * PN)

// Valid (s,e) pairs written by the pyramid (traced from _pool_specs):
//   scale0: d=e-s in [0,15], any s
//   scale1: d in {17,19,...,31} (odd), s even
//   scale2: d in {35,39,...,63} (d%4==3), s%4==0
__device__ __forceinline__ bool pair_valid(int s, int e) {
    int d = e - s;
    if (d < 0) return false;
    if (d <= 15) return true;
    if (d <= 31) return (d & 1) && !(s & 1);
    return d >= 35 && ((d & 3) == 3) && !(s & 3);
}

// ---------------------------------------------------------------------------
// K1: ori_map_h. One block (256 thr) handles 8 (b,h) rows.
// Sparse max table per row in LDS: level k holds max x[i..i+2^k-1].
// Window max [s,e] = max(L[k][s], L[k][e+1-2^k]), k = min(floor(log2(d+1)),5).
// Invalid pairs resolve to a zero slot -> branch-free emit, float4 stores.
// ---------------------------------------------------------------------------
#define K1_ROWS 8
#define K1_RS 385   // 6 levels * 64 + 1 zero slot

__global__ __launch_bounds__(256) void map_kernel(const float* __restrict__ x,
                                                  float* __restrict__ out) {
    __shared__ float L[K1_ROWS * K1_RS];   // 12.3 KB
    const int tid = threadIdx.x;

    // Per-thread metadata for its 16 (s,e) pairs — identical for all 8 rows.
    int a1[16], a2[16];
#pragma unroll
    for (int j = 0; j < 4; ++j) {
#pragma unroll
        for (int q = 0; q < 4; ++q) {
            const int idx = j * 4 + q;
            const int lin = j * 1024 + tid * 4 + q;   // s*64+e
            const int s = lin >> 6, e = lin & 63;
            const bool good = pair_valid(s, e);
            const int du = (e - s) + 1;
            const int k = good ? min(31 - __clz(du), 5) : 0;
            a1[idx] = good ? k * 64 + s : 384;                 // 384 = zero slot
            a2[idx] = good ? k * 64 + (e + 1 - (1 << k)) : 384;
        }
    }

    // Stage 8 x-rows (level 0) + zero slots.
    const size_t rowBase = (size_t)blockIdx.x * K1_ROWS;
#pragma unroll
    for (int i = tid; i < K1_ROWS * 64; i += 256) {
        const int r = i >> 6, c = i & 63;
        L[r * K1_RS + c] = x[rowBase * 64 + i];       // coalesced
    }
    if (tid < K1_ROWS) L[tid * K1_RS + 384] = 0.0f;
    __syncthreads();

    // Build levels 1..5 (entries past the queried range are garbage-but-unread).
#pragma unroll
    for (int k = 1; k <= 5; ++k) {
        const int off = 1 << (k - 1);
#pragma unroll
        for (int i = tid; i < K1_ROWS * 64; i += 256) {
            const int r = i >> 6, c = i & 63;
            const float* Lp = L + r * K1_RS + (k - 1) * 64;
            L[r * K1_RS + k * 64 + c] = fmaxf(Lp[c], Lp[min(c + off, 63)]);
        }
        __syncthreads();
    }

    // Emit 8 rows, float4 stores (1 KB per wave store-instruction).
#pragma unroll 1
    for (int r = 0; r < K1_ROWS; ++r) {
        const float* Lr = L + r * K1_RS;
        float4* orow = (float4*)(out + OFF_MAP + (rowBase + r) * 4096);
#pragma unroll
        for (int j = 0; j < 4; ++j) {
            float4 v;
            v.x = fmaxf(Lr[a1[j * 4 + 0]], Lr[a2[j * 4 + 0]]);
            v.y = fmaxf(Lr[a1[j * 4 + 1]], Lr[a2[j * 4 + 1]]);
            v.z = fmaxf(Lr[a1[j * 4 + 2]], Lr[a2[j * 4 + 2]]);
            v.w = fmaxf(Lr[a1[j * 4 + 3]], Lr[a2[j * 4 + 3]]);
            orow[j * 256 + tid] = v;
        }
    }
}

// ---------------------------------------------------------------------------
// K2: props_h. Grid (h-tiles=16, b=32) = 512 fat blocks (exactly 2/CU).
// Per block: build the 6-level sparse table for 32 h-lanes ONCE, resolve all
// 2080 props to LDS addr pairs ONCE, then one branch-free emit loop.
// Table reads are stride-1 over 32 lanes (2-way bank alias = free).
// ---------------------------------------------------------------------------
#define K2_LVL 2112            // 64 * 33 floats per level
#define K2_ZROW (6 * K2_LVL)   // 12672: zero row (33 floats)
#define K2_PA (K2_ZROW + 33)   // 12705: prop addr pairs (2*PP ints)

__global__ __launch_bounds__(256) void props_kernel(const float* __restrict__ x,
                                                    const int* __restrict__ props,
                                                    float* __restrict__ out) {
    __shared__ float Lf[K2_PA + 2 * PP];   // 16865 floats = 65.9 KiB -> 2 blocks/CU
    int* Li = (int*)Lf;

    const int tid = threadIdx.x;
    const int b  = blockIdx.y;
    const int h0 = blockIdx.x * 32;

    // Stage x[b, h0:h0+32, :] transposed: xT[n][h] at n*33+h (level 0).
    const float* xb = x + ((size_t)b * PH + h0) * PN;
#pragma unroll
    for (int i = tid; i < 32 * 64; i += 256) {
        const int h = i >> 6, n = i & 63;
        Lf[n * 33 + h] = xb[i];               // coalesced read
    }
    if (tid < 33) Lf[K2_ZROW + tid] = 0.0f;

    // Resolve ALL props to LDS address pairs (coalesced int2 loads).
    for (int p = tid; p < PP; p += 256) {
        const int2 pr = ((const int2*)props)[p];
        const int s  = pr.x;
        const int e1 = pr.y - 1;
        const bool good = pair_valid(s, e1);  // covers e1 < s
        const int k = good ? min(31 - __clz(e1 - s + 1), 5) : 0;
        Li[K2_PA + 2 * p]     = good ? k * K2_LVL + s * 33 : K2_ZROW;
        Li[K2_PA + 2 * p + 1] = good ? k * K2_LVL + (e1 + 1 - (1 << k)) * 33 : K2_ZROW;
    }
    __syncthreads();

    // Build levels 1..5.
#pragma unroll 1
    for (int k = 1; k <= 5; ++k) {
        const int off = 1 << (k - 1);
#pragma unroll
        for (int i = tid; i < 64 * 32; i += 256) {
            const int n = i >> 5, h = i & 31;
            const float* Lp = Lf + (k - 1) * K2_LVL;
            Lf[k * K2_LVL + n * 33 + h] = fmaxf(Lp[n * 33 + h], Lp[min(n + off, 63) * 33 + h]);
        }
        __syncthreads();
    }

    // Emit: each wave covers 2 props/step (lanes 0-31 = prop A, 32-63 = prop B).
    const int wave = tid >> 6;
    const int sub  = (tid >> 5) & 1;
    const int h    = tid & 31;
    float* ob = out + (size_t)b * PP * PH + h0 + h;
#pragma unroll 4
    for (int i = 0; i < PP / 8; ++i) {        // 260 steps
        const int idx = i * 8 + wave * 2 + sub;
        const int2 aa = *(const int2*)&Li[K2_PA + 2 * idx];  // ds_read_b64, 2-way bcast
        const float v = fmaxf(Lf[aa.x + h], Lf[aa.y + h]);   // stride-1 reads
        ob[(size_t)idx * PH] = v;             // 2x128B lines per wave store
    }
}

// ---------------------------------------------------------------------------
// K3a: base mask (valid pairs -> 1, else 0), float4 stores.
// ---------------------------------------------------------------------------
__global__ void mask_base_kernel(float* __restrict__ out) {
    const int gid = blockIdx.x * blockDim.x + threadIdx.x;  // over PB*1024
    const int l4 = (gid & 1023) * 4;                        // linear within 64x64
    float4 v;
    float* vv = (float*)&v;
#pragma unroll
    for (int q = 0; q < 4; ++q) {
        const int lin = l4 + q;
        vv[q] = pair_valid(lin >> 6, lin & 63) ? 1.0f : 0.0f;
    }
    ((float4*)(out + OFF_MASK))[gid] = v;
}

// K3b: scatter 1.0 at prop pairs (after K3a on the stream).
__global__ void mask_props_kernel(const int* __restrict__ props,
                                  float* __restrict__ out) {
    const int idx = blockIdx.x * blockDim.x + threadIdx.x;
    if (idx >= PB * PP) return;
    const int b = idx / PP;
    const int p = idx - b * PP;
    const int s  = props[2 * p];
    const int e1 = props[2 * p + 1] - 1;
    out[OFF_MASK + (size_t)b * (PN * PN) + s * PN + e1] = 1.0f;
}

extern "C" void kernel_launch(void* const* d_in, const int* in_sizes, int n_in,
                              void* d_out, int out_size, void* d_ws, size_t ws_size,
                              hipStream_t stream) {
    const float* x = (const float*)d_in[0];
    const int* props = (const int*)d_in[1];   // integer inputs arrive as int32
    float* out = (float*)d_out;

    map_kernel<<<(PB * PH) / K1_ROWS, 256, 0, stream>>>(x, out);

    dim3 g2(PH / 32, PB);
    props_kernel<<<g2, 256, 0, stream>>>(x, props, out);

    mask_base_kernel<<<(PB * 1024) / 256, 256, 0, stream>>>(out);
    mask_props_kernel<<<(PB * PP + 255) / 256, 256, 0, stream>>>(props, out);
}

// Round 5
// 411.745 us; speedup vs baseline: 1.2281x; 1.1744x over previous
//
#include <hip/hip_runtime.h>
#include <math.h>

// Problem constants: B=32, H=512, N=64, NUM_PROPS=2080
#define PB 32
#define PH 512
#define PN 64
#define PP 2080

// out layout (floats), reference return order:
//   [0,        OFF_MAP)   props_h  (B, P, H)
//   [OFF_MAP,  OFF_MASK)  ori_map_h(B, H, 64, 64)
//   [OFF_MASK, ...)       mask     (B, 1, 64, 64)
#define OFF_MAP  ((size_t)PB * PP * PH)
#define OFF_MASK (OFF_MAP + (size_t)PB * PH * PN * PN)

// Valid (s,e) pairs written by the pyramid (traced from _pool_specs):
//   scale0: d=e-s in [0,15], any s
//   scale1: d in {17,19,...,31} (odd), s even
//   scale2: d in {35,39,...,63} (d%4==3), s%4==0
__device__ __forceinline__ bool pair_valid(int s, int e) {
    int d = e - s;
    if (d < 0) return false;
    if (d <= 15) return true;
    if (d <= 31) return (d & 1) && !(s & 1);
    return d >= 35 && ((d & 3) == 3) && !(s & 3);
}

// ---------------------------------------------------------------------------
// K1: ori_map_h. One block (256 thr = 4 waves) handles 8 (b,h) rows.
// Sparse max table per row in LDS, levels SKEWED: slot(k,c) = 65*k + c
//   (stride 65 == 1 mod 32 -> level base lands on distinct banks).
// Wave-per-s layout: e = lane, wave w iterates s = 16w..16w+15.
//   a1 = slot(k,s): <=6 distinct addrs on distinct banks (broadcast, free)
//   a2 = slot(k,e+1-2^k): lane-stride 1 within each k-run (conflict-free)
// Invalid pairs -> zero slot (same addr for all -> broadcast). Stores: each
// wave writes 256 B contiguous (full lines) per (row,s).
// ---------------------------------------------------------------------------
#define K1_ROWS 8
#define K1_RS 392          // 389 used (slot max 388) + zero slot at 390
#define K1_ZERO 390

__global__ __launch_bounds__(256) void map_kernel(const float* __restrict__ x,
                                                  float* __restrict__ out) {
    __shared__ float L[K1_ROWS * K1_RS];   // 12.5 KB
    const int tid  = threadIdx.x;
    const int wave = tid >> 6;
    const int lane = tid & 63;             // = e

    // Per-thread metadata for its 16 s-values (same for all 8 rows).
    int a1[16], a2[16];
#pragma unroll
    for (int i = 0; i < 16; ++i) {
        const int s = wave * 16 + i;
        const int e = lane;
        const bool good = pair_valid(s, e);
        const int k = good ? min(31 - __clz(e - s + 1), 5) : 0;
        a1[i] = good ? 65 * k + s : K1_ZERO;
        a2[i] = good ? 65 * k + (e + 1 - (1 << k)) : K1_ZERO;
    }

    // Stage 8 x-rows (level 0 = slots 0..63) + zero slots.
    const size_t rowBase = (size_t)blockIdx.x * K1_ROWS;
#pragma unroll
    for (int i = tid; i < K1_ROWS * 64; i += 256) {
        const int r = i >> 6, c = i & 63;
        L[r * K1_RS + c] = x[rowBase * 64 + i];       // coalesced
    }
    if (tid < K1_ROWS) L[tid * K1_RS + K1_ZERO] = 0.0f;
    __syncthreads();

    // Build levels 1..5 (entries past the queried range are garbage-but-unread).
#pragma unroll
    for (int k = 1; k <= 5; ++k) {
        const int off = 1 << (k - 1);
#pragma unroll
        for (int i = tid; i < K1_ROWS * 64; i += 256) {
            const int r = i >> 6, c = i & 63;
            const float* Lp = L + r * K1_RS + 65 * (k - 1);
            L[r * K1_RS + 65 * k + c] = fmaxf(Lp[c], Lp[min(c + off, 63)]);
        }
        __syncthreads();
    }

    // Emit: 8 rows x 16 s-values, 256 B full-line wave stores.
#pragma unroll 2
    for (int r = 0; r < K1_ROWS; ++r) {
        const float* Lr = L + r * K1_RS;
        float* orow = out + OFF_MAP + (rowBase + r) * 4096 + lane;
#pragma unroll
        for (int i = 0; i < 16; ++i) {
            orow[(wave * 16 + i) * 64] = fmaxf(Lr[a1[i]], Lr[a2[i]]);
        }
    }
}

// ---------------------------------------------------------------------------
// K2: props_h. Grid (h-tiles=16, b=32) = 512 fat blocks (exactly 2/CU).
// Per block: build the 6-level sparse table for 32 h-lanes ONCE, resolve all
// 2080 props to LDS addr pairs ONCE (8B-aligned int2), then one branch-free
// emit loop: ds_read_b64 addr (broadcast) + 2 stride-1 table reads + store.
// ---------------------------------------------------------------------------
#define K2_LVL 2112            // 64 * 33 floats per level
#define K2_ZROW (6 * K2_LVL)   // 12672: zero row (33 floats)
#define K2_PA 12706            // prop addr pairs (2*PP ints), EVEN -> b64-aligned

__global__ __launch_bounds__(256) void props_kernel(const float* __restrict__ x,
                                                    const int* __restrict__ props,
                                                    float* __restrict__ out) {
    __shared__ float Lf[K2_PA + 2 * PP];   // 16866 floats = 65.9 KiB -> 2 blocks/CU
    int* Li = (int*)Lf;

    const int tid = threadIdx.x;
    const int b  = blockIdx.y;
    const int h0 = blockIdx.x * 32;

    // Stage x[b, h0:h0+32, :] transposed: xT[n][h] at n*33+h (level 0).
    const float* xb = x + ((size_t)b * PH + h0) * PN;
#pragma unroll
    for (int i = tid; i < 32 * 64; i += 256) {
        const int h = i >> 6, n = i & 63;
        Lf[n * 33 + h] = xb[i];               // coalesced read
    }
    if (tid < 33) Lf[K2_ZROW + tid] = 0.0f;

    // Resolve ALL props to LDS address pairs (coalesced int2 loads).
    for (int p = tid; p < PP; p += 256) {
        const int2 pr = ((const int2*)props)[p];
        const int s  = pr.x;
        const int e1 = pr.y - 1;
        const bool good = pair_valid(s, e1);  // covers e1 < s
        const int k = good ? min(31 - __clz(e1 - s + 1), 5) : 0;
        Li[K2_PA + 2 * p]     = good ? k * K2_LVL + s * 33 : K2_ZROW;
        Li[K2_PA + 2 * p + 1] = good ? k * K2_LVL + (e1 + 1 - (1 << k)) * 33 : K2_ZROW;
    }
    __syncthreads();

    // Build levels 1..5.
#pragma unroll 1
    for (int k = 1; k <= 5; ++k) {
        const int off = 1 << (k - 1);
#pragma unroll
        for (int i = tid; i < 64 * 32; i += 256) {
            const int n = i >> 5, h = i & 31;
            const float* Lp = Lf + (k - 1) * K2_LVL;
            Lf[k * K2_LVL + n * 33 + h] = fmaxf(Lp[n * 33 + h], Lp[min(n + off, 63) * 33 + h]);
        }
        __syncthreads();
    }

    // Emit: each wave covers 2 props/step (lanes 0-31 = prop A, 32-63 = prop B).
    const int wave = tid >> 6;
    const int sub  = (tid >> 5) & 1;
    const int h    = tid & 31;
    float* ob = out + (size_t)b * PP * PH + h0 + h;
#pragma unroll 4
    for (int i = 0; i < PP / 8; ++i) {        // 260 steps
        const int idx = i * 8 + wave * 2 + sub;
        const int2 aa = *(const int2*)&Li[K2_PA + 2 * idx];  // ds_read_b64, broadcast
        const float v = fmaxf(Lf[aa.x + h], Lf[aa.y + h]);   // stride-1 reads
        ob[(size_t)idx * PH] = v;             // 2x128B full lines per wave store
    }
}

// ---------------------------------------------------------------------------
// K3a: base mask (valid pairs -> 1, else 0), float4 stores.
// ---------------------------------------------------------------------------
__global__ void mask_base_kernel(float* __restrict__ out) {
    const int gid = blockIdx.x * blockDim.x + threadIdx.x;  // over PB*1024
    const int l4 = (gid & 1023) * 4;                        // linear within 64x64
    float4 v;
    float* vv = (float*)&v;
#pragma unroll
    for (int q = 0; q < 4; ++q) {
        const int lin = l4 + q;
        vv[q] = pair_valid(lin >> 6, lin & 63) ? 1.0f : 0.0f;
    }
    ((float4*)(out + OFF_MASK))[gid] = v;
}

// K3b: scatter 1.0 at prop pairs (after K3a on the stream).
__global__ void mask_props_kernel(const int* __restrict__ props,
                                  float* __restrict__ out) {
    const int idx = blockIdx.x * blockDim.x + threadIdx.x;
    if (idx >= PB * PP) return;
    const int b = idx / PP;
    const int p = idx - b * PP;
    const int s  = props[2 * p];
    const int e1 = props[2 * p + 1] - 1;
    out[OFF_MASK + (size_t)b * (PN * PN) + s * PN + e1] = 1.0f;
}

extern "C" void kernel_launch(void* const* d_in, const int* in_sizes, int n_in,
                              void* d_out, int out_size, void* d_ws, size_t ws_size,
                              hipStream_t stream) {
    const float* x = (const float*)d_in[0];
    const int* props = (const int*)d_in[1];   // integer inputs arrive as int32
    float* out = (float*)d_out;

    map_kernel<<<(PB * PH) / K1_ROWS, 256, 0, stream>>>(x, out);

    dim3 g2(PH / 32, PB);
    props_kernel<<<g2, 256, 0, stream>>>(x, props, out);

    mask_base_kernel<<<(PB * 1024) / 256, 256, 0, stream>>>(out);
    mask_props_kernel<<<(PB * PP + 255) / 256, 256, 0, stream>>>(props, out);
}